// Round 15
// baseline (135.746 us; speedup 1.0000x reference)
//
#include <hip/hip_runtime.h>
#include <hip/hip_bf16.h>

#define NB   4      // batch
#define CIN  512    // in channels
#define NPX  16384  // H*W
#define KC   256    // key channels
#define KP   150    // proxy regions

// LDS row strides (u16 units). Multiples of 8 (16B alignment for b128).
#define LDH  264    // H1/Q/CX rows [64][256] padded
#define LDP  200    // P rows [64][160] padded
#define LDX  76     // XB rows [64][64] padded
#define SHSZ 16896  // u16: 64*264 = 33792 B total LDS
#define XBOF 7168   // XB dbuf base (2 x 4864 u16) at exact tail of H1 region

typedef __attribute__((ext_vector_type(8))) short short8;
typedef __attribute__((ext_vector_type(4))) float f32x4;
typedef __attribute__((ext_vector_type(4))) unsigned int u32x4;
typedef unsigned short u16;

__device__ __forceinline__ u16 f2bf(float f) {
    unsigned int u = __float_as_uint(f);
    return (u16)((u + 0x7FFFu + ((u >> 16) & 1u)) >> 16);
}
// HW packed fp32->bf16 (RNE): lo -> bits[15:0], hi -> bits[31:16]
__device__ __forceinline__ unsigned cvtpk(float lo, float hi) {
    unsigned r;
    asm("v_cvt_pk_bf16_f32 %0, %1, %2" : "=v"(r) : "v"(lo), "v"(hi));
    return r;
}
// fragment load from pre-packed global: idx = (R*NS+S)*64 + lane
__device__ __forceinline__ short8 ldfrag(const u16* __restrict__ p, int idx) {
    return *(const short8*)(p + ((long)idx << 3));
}

// ===========================================================================
// Fused: x(fp32) -> G1 -> G2 -> G3 -> softmax -> G4 -> G5 -> out(fp32)
// per 64-pixel tile. 256 thr = 4 waves. A-operands = packed frags in global.
// r15 = r13 body verbatim (all unroll-1 pins KEPT — r14 proved they are
// load-bearing for correctness with the aliased LDS overlays) with ONLY the
// s_setprio wrappers removed (m190: null-to-negative on lockstep GEMM).
// ===========================================================================
__global__ __launch_bounds__(256, 4)
void fused_kernel(const u16* __restrict__ wp1p, const float* __restrict__ xg,
                  const u16* __restrict__ wp2p, const float* __restrict__ bp1,
                  const float* __restrict__ bp2, const u16* __restrict__ keyp,
                  const u16* __restrict__ vp, const u16* __restrict__ wup,
                  const float* __restrict__ bu, float* __restrict__ outg)
{
    __shared__ u16 sh[SHSZ];

    const int b  = blockIdx.z;
    const int n0 = blockIdx.x * 64;
    const int tid = threadIdx.x, lane = tid & 63, wid = tid >> 6;
    const int rg = lane & 15, kg = lane >> 4;

    const float* xb = xg + (long)b * CIN * NPX;
    float* ob       = outg + (long)b * CIN * NPX;
    const u16* kyp  = keyp + (long)b * 40960;
    const u16* vbp  = vp   + (long)b * 40960;

    // ------------------------- phase 1: G1 (K=512) -------------------------
    const int sxp = (tid & 31) * 2, sxg = tid >> 5;
    const float* xsrc = xb + (long)(sxg * 8) * NPX + n0 + sxp;
    u16* XB = sh + XBOF;

    float f0[8], f1[8];
    auto LOADX = [&](int kt) {
        #pragma unroll
        for (int e = 0; e < 8; ++e) {
            float2 v = *(const float2*)(xsrc + (long)(kt * 64 + e) * NPX);
            f0[e] = v.x; f1[e] = v.y;
        }
    };
    auto WRITEX = [&](int buf) {
        u32x4 w0, w1;
        w0.x = cvtpk(f0[0], f0[1]); w0.y = cvtpk(f0[2], f0[3]);
        w0.z = cvtpk(f0[4], f0[5]); w0.w = cvtpk(f0[6], f0[7]);
        w1.x = cvtpk(f1[0], f1[1]); w1.y = cvtpk(f1[2], f1[3]);
        w1.z = cvtpk(f1[4], f1[5]); w1.w = cvtpk(f1[6], f1[7]);
        *(u32x4*)(XB + buf * 4864 + sxp * LDX + sxg * 8) = w0;
        *(u32x4*)(XB + buf * 4864 + (sxp + 1) * LDX + sxg * 8) = w1;
    };

    f32x4 acc[4][4];
    #pragma unroll
    for (int i = 0; i < 4; ++i)
        #pragma unroll
        for (int j = 0; j < 4; ++j) acc[i][j] = (f32x4){0.f, 0.f, 0.f, 0.f};

    LOADX(0); WRITEX(0);
    __syncthreads();

    #pragma unroll 1
    for (int kt = 0; kt < 8; ++kt) {
        const int buf = kt & 1;
        if (kt < 7) LOADX(kt + 1);
        #pragma unroll 1
        for (int s = 0; s < 2; ++s) {
            short8 a[4];
            #pragma unroll
            for (int i = 0; i < 4; ++i)
                a[i] = ldfrag(wp1p, ((wid * 4 + i) * 16 + kt * 2 + s) * 64 + lane);
            #pragma unroll
            for (int j = 0; j < 4; ++j) {
                short8 bb = *(const short8*)(XB + buf * 4864 + (j * 16 + rg) * LDX + (s * 4 + kg) * 8);
                #pragma unroll
                for (int i = 0; i < 4; ++i)
                    acc[i][j] = __builtin_amdgcn_mfma_f32_16x16x32_bf16(a[i], bb, acc[i][j], 0, 0, 0);
            }
        }
        if (kt < 7) WRITEX(buf ^ 1);
        __syncthreads();
    }

    // h1 -> LDS [n][kc] (stride LDH), bias+relu, cvt_pk
    #pragma unroll
    for (int i = 0; i < 4; ++i) {
        const int kc4 = wid * 64 + i * 16 + kg * 4;
        const f32x4 bv = *(const f32x4*)(bp1 + kc4);
        #pragma unroll
        for (int j = 0; j < 4; ++j) {
            const int n = j * 16 + rg;
            uint2 pk;
            pk.x = cvtpk(fmaxf(acc[i][j][0] + bv.x, 0.f), fmaxf(acc[i][j][1] + bv.y, 0.f));
            pk.y = cvtpk(fmaxf(acc[i][j][2] + bv.z, 0.f), fmaxf(acc[i][j][3] + bv.w, 0.f));
            *(uint2*)(sh + n * LDH + kc4) = pk;
        }
    }
    __syncthreads();

    // ------------------------- phase 2: G2 (K=256) -------------------------
    f32x4 acc2[4][4];
    #pragma unroll
    for (int i = 0; i < 4; ++i)
        #pragma unroll
        for (int j = 0; j < 4; ++j) acc2[i][j] = (f32x4){0.f, 0.f, 0.f, 0.f};

    #pragma unroll 1
    for (int S = 0; S < 8; ++S) {
        short8 a[4];
        #pragma unroll
        for (int i = 0; i < 4; ++i)
            a[i] = ldfrag(wp2p, ((wid * 4 + i) * 8 + S) * 64 + lane);
        #pragma unroll
        for (int j = 0; j < 4; ++j) {
            short8 bb = *(const short8*)(sh + (j * 16 + rg) * LDH + S * 32 + kg * 8);
            #pragma unroll
            for (int i = 0; i < 4; ++i)
                acc2[i][j] = __builtin_amdgcn_mfma_f32_16x16x32_bf16(a[i], bb, acc2[i][j], 0, 0, 0);
        }
    }
    __syncthreads();   // all H1 reads done

    // q2 -> same LDS region, bias+relu, cvt_pk
    #pragma unroll
    for (int i = 0; i < 4; ++i) {
        const int kc4 = wid * 64 + i * 16 + kg * 4;
        const f32x4 bv = *(const f32x4*)(bp2 + kc4);
        #pragma unroll
        for (int j = 0; j < 4; ++j) {
            const int n = j * 16 + rg;
            uint2 pk;
            pk.x = cvtpk(fmaxf(acc2[i][j][0] + bv.x, 0.f), fmaxf(acc2[i][j][1] + bv.y, 0.f));
            pk.y = cvtpk(fmaxf(acc2[i][j][2] + bv.z, 0.f), fmaxf(acc2[i][j][3] + bv.w, 0.f));
            *(uint2*)(sh + n * LDH + kc4) = pk;
        }
    }
    __syncthreads();

    // ------------------- phase 3: G3 + in-register softmax ------------------
    f32x4 s1[10];
    #pragma unroll
    for (int i = 0; i < 10; ++i) s1[i] = (f32x4){0.f, 0.f, 0.f, 0.f};
    #pragma unroll 1
    for (int s = 0; s < 8; ++s) {
        short8 bq = *(const short8*)(sh + (wid * 16 + rg) * LDH + s * 32 + kg * 8);
        #pragma unroll
        for (int i = 0; i < 10; ++i) {
            short8 a = ldfrag(kyp, (i * 8 + s) * 64 + lane);
            s1[i] = __builtin_amdgcn_mfma_f32_16x16x32_bf16(a, bq, s1[i], 0, 0, 0);
        }
    }
    float mx = -3.0e38f;
    #pragma unroll
    for (int i = 0; i < 9; ++i)
        #pragma unroll
        for (int r = 0; r < 4; ++r) mx = fmaxf(mx, s1[i][r]);
    #pragma unroll
    for (int r = 0; r < 4; ++r) if (kg * 4 + r < 6) mx = fmaxf(mx, s1[9][r]);
    mx = fmaxf(mx, __shfl_xor(mx, 16));
    mx = fmaxf(mx, __shfl_xor(mx, 32));
    float l = 0.f;
    #pragma unroll
    for (int i = 0; i < 10; ++i)
        #pragma unroll
        for (int r = 0; r < 4; ++r) {
            const bool valid = (i < 9) || (kg * 4 + r < 6);
            float e = valid ? __expf((s1[i][r] - mx) * 0.0625f) : 0.f;
            s1[i][r] = e; l += e;
        }
    l += __shfl_xor(l, 16);
    l += __shfl_xor(l, 32);
    const float inv = 1.f / l;
    __syncthreads();   // all Q reads done

    // P -> LDS [n][kp] (stride LDP), normalized bf16, cvt_pk
    #pragma unroll
    for (int i = 0; i < 10; ++i) {
        uint2 pk;
        pk.x = cvtpk(s1[i][0] * inv, s1[i][1] * inv);
        pk.y = cvtpk(s1[i][2] * inv, s1[i][3] * inv);
        *(uint2*)(sh + (wid * 16 + rg) * LDP + i * 16 + kg * 4) = pk;
    }
    __syncthreads();

    // ------------------------- phase 4: G4 (K=160) -------------------------
    f32x4 acc4[4][4];
    #pragma unroll
    for (int i = 0; i < 4; ++i)
        #pragma unroll
        for (int j = 0; j < 4; ++j) acc4[i][j] = (f32x4){0.f, 0.f, 0.f, 0.f};
    #pragma unroll 1
    for (int s = 0; s < 5; ++s) {
        short8 a[4];
        #pragma unroll
        for (int i = 0; i < 4; ++i)
            a[i] = ldfrag(vbp, ((wid * 4 + i) * 5 + s) * 64 + lane);
        #pragma unroll
        for (int j = 0; j < 4; ++j) {
            short8 bb = *(const short8*)(sh + (j * 16 + rg) * LDP + s * 32 + kg * 8);
            #pragma unroll
            for (int i = 0; i < 4; ++i)
                acc4[i][j] = __builtin_amdgcn_mfma_f32_16x16x32_bf16(a[i], bb, acc4[i][j], 0, 0, 0);
        }
    }
    __syncthreads();   // all P reads done

    // context -> LDS [n][kc] (stride LDH), cvt_pk
    #pragma unroll
    for (int i = 0; i < 4; ++i) {
        const int kc4 = wid * 64 + i * 16 + kg * 4;
        #pragma unroll
        for (int j = 0; j < 4; ++j) {
            const int n = j * 16 + rg;
            uint2 pk;
            pk.x = cvtpk(acc4[i][j][0], acc4[i][j][1]);
            pk.y = cvtpk(acc4[i][j][2], acc4[i][j][3]);
            *(uint2*)(sh + n * LDH + kc4) = pk;
        }
    }
    __syncthreads();

    // ---------------- phase 5: G5 (K=256, M=512, two halves) ----------------
    #pragma unroll 1
    for (int h2 = 0; h2 < 2; ++h2) {
        f32x4 a5[4][4];
        #pragma unroll
        for (int i = 0; i < 4; ++i)
            #pragma unroll
            for (int j = 0; j < 4; ++j) a5[i][j] = (f32x4){0.f, 0.f, 0.f, 0.f};
        #pragma unroll 1
        for (int S = 0; S < 8; ++S) {
            short8 a[4];
            #pragma unroll
            for (int i = 0; i < 4; ++i)
                a[i] = ldfrag(wup, ((h2 * 16 + wid * 4 + i) * 8 + S) * 64 + lane);
            #pragma unroll
            for (int j = 0; j < 4; ++j) {
                short8 bb = *(const short8*)(sh + (j * 16 + rg) * LDH + S * 32 + kg * 8);
                #pragma unroll
                for (int i = 0; i < 4; ++i)
                    a5[i][j] = __builtin_amdgcn_mfma_f32_16x16x32_bf16(a[i], bb, a5[i][j], 0, 0, 0);
            }
        }
        #pragma unroll
        for (int i = 0; i < 4; ++i) {
            const int c4 = h2 * 256 + wid * 64 + i * 16 + kg * 4;
            const f32x4 bv = *(const f32x4*)(bu + c4);
            #pragma unroll
            for (int j = 0; j < 4; ++j) {
                const int n = n0 + j * 16 + rg;
                ob[(long)(c4 + 0) * NPX + n] = fmaxf(a5[i][j][0] + bv.x, 0.f);
                ob[(long)(c4 + 1) * NPX + n] = fmaxf(a5[i][j][1] + bv.y, 0.f);
                ob[(long)(c4 + 2) * NPX + n] = fmaxf(a5[i][j][2] + bv.z, 0.f);
                ob[(long)(c4 + 3) * NPX + n] = fmaxf(a5[i][j][3] + bv.w, 0.f);
            }
        }
    }
}

// ===========================================================================
// prep: blocks 0..511 pack wp1/wp2/wu into MFMA A-frag bf16 order; blocks
// 512..591: LDS-tiled 64x64 transposes of w_o1/w_d/w_o2 to [c][kc] fp32.
// ===========================================================================
__global__ __launch_bounds__(256)
void prep_kernel(const float* __restrict__ w_p1, const float* __restrict__ w_p2,
                 const float* __restrict__ w_u,  const float* __restrict__ w_o1,
                 const float* __restrict__ w_o2, const float* __restrict__ w_d,
                 u16* __restrict__ wp1p, u16* __restrict__ wp2p,
                 u16* __restrict__ wup, float* __restrict__ wo1T,
                 float* __restrict__ wdT, float* __restrict__ wo2T)
{
    const int bx = blockIdx.x;
    const int tid = threadIdx.x;
    if (bx < 512) {
        const int i = bx * 256 + tid;   // < 131072
        const int j = i & 7, l = (i >> 3) & 63;
        {   // wp1: M=256, K=512, NS=16
            const int S = (i >> 9) & 15, R = i >> 13;
            wp1p[i] = f2bf(w_p1[(long)(R * 16 + (l & 15)) * CIN + S * 32 + ((l >> 4) << 3) + j]);
        }
        {   // wu: M=512, K=256, NS=8
            const int S = (i >> 9) & 7, R = i >> 12;
            wup[i] = f2bf(w_u[(long)(R * 16 + (l & 15)) * KC + S * 32 + ((l >> 4) << 3) + j]);
        }
        if (i < 65536) {
            // wp2: M=256, K=256, NS=8
            const int S = (i >> 9) & 7, R = i >> 12;
            wp2p[i] = f2bf(w_p2[(long)(R * 16 + (l & 15)) * KC + S * 32 + ((l >> 4) << 3) + j]);
        }
        return;
    }
    // ---- transpose tiles: src [256][C] -> dst [C][256] ----
    __shared__ float T[64][65];
    int tb = bx - 512;
    const float* src; float* dst; int srcC;
    if (tb < 32)      { src = w_o1; dst = wo1T; srcC = CIN; }
    else if (tb < 64) { tb -= 32; src = w_d; dst = wdT; srcC = CIN; }
    else              { tb -= 64; src = w_o2; dst = wo2T; srcC = KC; }
    const int r0 = (tb & 3) * 64, c0 = (tb >> 2) * 64;
    const int lr = tid >> 6, lc = tid & 63;
    #pragma unroll
    for (int p = 0; p < 16; ++p)
        T[p * 4 + lr][lc] = src[(long)(r0 + p * 4 + lr) * srcC + c0 + lc];
    __syncthreads();
    #pragma unroll
    for (int p = 0; p < 16; ++p)
        dst[(long)(c0 + p * 4 + lr) * KC + r0 + lc] = T[lc][p * 4 + lr];
}

// ===========================================================================
// kv: merged kv1+kv2 — block = 2 kp rows x 256 kc threads, grid (80, NB).
// ===========================================================================
__global__ __launch_bounds__(256)
void kv_kernel(const float* __restrict__ proxy,
               const float* __restrict__ wo1T, const float* __restrict__ b_o1,
               const float* __restrict__ wdT,  const float* __restrict__ b_d,
               const float* __restrict__ wo2T, const float* __restrict__ b_o2,
               u16* __restrict__ keyp, u16* __restrict__ vp)
{
    __shared__ float PX[CIN * 2];   // proxy [c][q]  4 KB
    __shared__ float HL[2][KC];     // hidden[q][kc] 2 KB
    const int kp0 = blockIdx.x * 2;
    const int b   = blockIdx.y;
    const int kc  = threadIdx.x;    // 0..255

    #pragma unroll
    for (int it = 0; it < 4; ++it) {
        const int idx = it * 256 + kc;
        const int q = idx & 1, c = idx >> 1;
        const int kp = kp0 + q;
        PX[c * 2 + q] = (kp < KP) ? proxy[(long)b * CIN * KP + (long)c * KP + kp] : 0.f;
    }
    __syncthreads();

    float ah[2] = {0.f, 0.f}, av[2] = {0.f, 0.f};
    #pragma unroll 1
    for (int c0 = 0; c0 < CIN; c0 += 8) {
        float w1[8], wd[8];
        #pragma unroll
        for (int e = 0; e < 8; ++e) {
            w1[e] = wo1T[(long)(c0 + e) * KC + kc];
            wd[e] = wdT [(long)(c0 + e) * KC + kc];
        }
        #pragma unroll
        for (int e = 0; e < 8; ++e)
            #pragma unroll
            for (int q = 0; q < 2; ++q) {
                const float p = PX[(c0 + e) * 2 + q];
                ah[q] += w1[e] * p;
                av[q] += wd[e] * p;
            }
    }
    const float bo1 = b_o1[kc], bd = b_d[kc];
    #pragma unroll
    for (int q = 0; q < 2; ++q) {
        const int kp = kp0 + q;
        HL[q][kc] = fmaxf(ah[q] + bo1, 0.f);
        const float vv = (kp < KP) ? fmaxf(av[q] + bd, 0.f) : 0.f;
        const int idx2 = (((kc >> 4) * 5 + (kp >> 5)) * 64 +
                          ((kp >> 3) & 3) * 16 + (kc & 15)) * 8 + (kp & 7);
        vp[(long)b * 40960 + idx2] = f2bf(vv);
    }
    __syncthreads();

    float ak[2] = {0.f, 0.f};
    #pragma unroll 1
    for (int c0 = 0; c0 < KC; c0 += 8) {
        float w2[8];
        #pragma unroll
        for (int e = 0; e < 8; ++e)
            w2[e] = wo2T[(long)(c0 + e) * KC + kc];
        #pragma unroll
        for (int e = 0; e < 8; ++e)
            #pragma unroll
            for (int q = 0; q < 2; ++q)
                ak[q] += w2[e] * HL[q][c0 + e];
    }
    const float bo2 = b_o2[kc];
    #pragma unroll
    for (int q = 0; q < 2; ++q) {
        const int kp = kp0 + q;
        const float v = (kp < KP) ? fmaxf(ak[q] + bo2, 0.f) : 0.f;
        const int idx = (((kp >> 4) * 8 + (kc >> 5)) * 64 +
                         ((kc >> 3) & 3) * 16 + (kp & 15)) * 8 + (kc & 7);
        keyp[(long)b * 40960 + idx] = f2bf(v);
    }
}

extern "C" void kernel_launch(void* const* d_in, const int* in_sizes, int n_in,
                              void* d_out, int out_size, void* d_ws, size_t ws_size,
                              hipStream_t stream)
{
    const float* x     = (const float*)d_in[0];
    const float* proxy = (const float*)d_in[1];
    const float* w_p1  = (const float*)d_in[2];
    const float* b_p1  = (const float*)d_in[3];
    const float* w_p2  = (const float*)d_in[4];
    const float* b_p2  = (const float*)d_in[5];
    const float* w_o1  = (const float*)d_in[6];
    const float* b_o1  = (const float*)d_in[7];
    const float* w_o2  = (const float*)d_in[8];
    const float* b_o2  = (const float*)d_in[9];
    const float* w_d   = (const float*)d_in[10];
    const float* b_d   = (const float*)d_in[11];
    const float* w_u   = (const float*)d_in[12];
    const float* b_u   = (const float*)d_in[13];
    float* out = (float*)d_out;
    (void)in_sizes; (void)n_in; (void)out_size; (void)ws_size;

    char* ws = (char*)d_ws;
    size_t off = 0;
    auto alloc = [&](size_t bytes) { size_t o = off; off += (bytes + 255) & ~(size_t)255; return o; };

    u16*   wp1p = (u16*)  (ws + alloc((size_t)131072 * 2));
    u16*   wp2p = (u16*)  (ws + alloc((size_t)65536 * 2));
    u16*   wup  = (u16*)  (ws + alloc((size_t)131072 * 2));
    float* wo1T = (float*)(ws + alloc((size_t)131072 * 4));
    float* wdT  = (float*)(ws + alloc((size_t)131072 * 4));
    float* wo2T = (float*)(ws + alloc((size_t)65536 * 4));
    u16*   keyp = (u16*)  (ws + alloc((size_t)NB * 40960 * 2));
    u16*   vp   = (u16*)  (ws + alloc((size_t)NB * 40960 * 2));

    prep_kernel<<<592, 256, 0, stream>>>(
        w_p1, w_p2, w_u, w_o1, w_o2, w_d, wp1p, wp2p, wup, wo1T, wdT, wo2T);
    kv_kernel<<<dim3(80, NB), 256, 0, stream>>>(
        proxy, wo1T, b_o1, wdT, b_d, wo2T, b_o2, keyp, vp);
    fused_kernel<<<dim3(NPX / 64, 1, NB), 256, 0, stream>>>(
        wp1p, x, wp2p, b_p1, b_p2, keyp, vp, wup, b_u, out);
}

// Round 16
// 130.084 us; speedup vs baseline: 1.0435x; 1.0435x over previous
//
#include <hip/hip_runtime.h>
#include <hip/hip_bf16.h>

#define NB   4      // batch
#define CIN  512    // in channels
#define NPX  16384  // H*W
#define KC   256    // key channels
#define KP   150    // proxy regions

// LDS row strides (u16 units). Multiples of 8 (16B alignment for b128).
#define LDH  264    // H1/Q/CX rows [64][256] padded
#define LDP  200    // P rows [64][160] padded
#define LDX  76     // XB rows [64][64] padded
#define SHSZ 16896  // u16: 64*264 = 33792 B total LDS
#define XBOF 7168   // XB dbuf base (2 x 4864 u16) at exact tail of H1 region

typedef __attribute__((ext_vector_type(8))) short short8;
typedef __attribute__((ext_vector_type(4))) float f32x4;
typedef __attribute__((ext_vector_type(4))) unsigned int u32x4;
typedef unsigned short u16;

__device__ __forceinline__ u16 f2bf(float f) {
    unsigned int u = __float_as_uint(f);
    return (u16)((u + 0x7FFFu + ((u >> 16) & 1u)) >> 16);
}
// HW packed fp32->bf16 (RNE): lo -> bits[15:0], hi -> bits[31:16]
__device__ __forceinline__ unsigned cvtpk(float lo, float hi) {
    unsigned r;
    asm("v_cvt_pk_bf16_f32 %0, %1, %2" : "=v"(r) : "v"(lo), "v"(hi));
    return r;
}
// fragment load from pre-packed global: idx = (R*NS+S)*64 + lane
__device__ __forceinline__ short8 ldfrag(const u16* __restrict__ p, int idx) {
    return *(const short8*)(p + ((long)idx << 3));
}

// ===========================================================================
// Fused: x(fp32) -> G1 -> G2 -> G3 -> softmax -> G4 -> G5 -> out(fp32)
// per 64-pixel tile. 256 thr = 4 waves. A-operands = packed frags in global
// (L2-resident, direct loads). r16 = r13 verbatim — the best verified config:
// setprio around MFMA bursts (+5%, r15 A/B), cvt_pk packing, unroll-1 pins
// (load-bearing over the aliased LDS overlays, r14), LDX=76 bank stride.
// ===========================================================================
__global__ __launch_bounds__(256, 4)
void fused_kernel(const u16* __restrict__ wp1p, const float* __restrict__ xg,
                  const u16* __restrict__ wp2p, const float* __restrict__ bp1,
                  const float* __restrict__ bp2, const u16* __restrict__ keyp,
                  const u16* __restrict__ vp, const u16* __restrict__ wup,
                  const float* __restrict__ bu, float* __restrict__ outg)
{
    __shared__ u16 sh[SHSZ];

    const int b  = blockIdx.z;
    const int n0 = blockIdx.x * 64;
    const int tid = threadIdx.x, lane = tid & 63, wid = tid >> 6;
    const int rg = lane & 15, kg = lane >> 4;

    const float* xb = xg + (long)b * CIN * NPX;
    float* ob       = outg + (long)b * CIN * NPX;
    const u16* kyp  = keyp + (long)b * 40960;
    const u16* vbp  = vp   + (long)b * 40960;

    // ------------------------- phase 1: G1 (K=512) -------------------------
    const int sxp = (tid & 31) * 2, sxg = tid >> 5;
    const float* xsrc = xb + (long)(sxg * 8) * NPX + n0 + sxp;
    u16* XB = sh + XBOF;

    float f0[8], f1[8];
    auto LOADX = [&](int kt) {
        #pragma unroll
        for (int e = 0; e < 8; ++e) {
            float2 v = *(const float2*)(xsrc + (long)(kt * 64 + e) * NPX);
            f0[e] = v.x; f1[e] = v.y;
        }
    };
    auto WRITEX = [&](int buf) {
        u32x4 w0, w1;
        w0.x = cvtpk(f0[0], f0[1]); w0.y = cvtpk(f0[2], f0[3]);
        w0.z = cvtpk(f0[4], f0[5]); w0.w = cvtpk(f0[6], f0[7]);
        w1.x = cvtpk(f1[0], f1[1]); w1.y = cvtpk(f1[2], f1[3]);
        w1.z = cvtpk(f1[4], f1[5]); w1.w = cvtpk(f1[6], f1[7]);
        *(u32x4*)(XB + buf * 4864 + sxp * LDX + sxg * 8) = w0;
        *(u32x4*)(XB + buf * 4864 + (sxp + 1) * LDX + sxg * 8) = w1;
    };

    f32x4 acc[4][4];
    #pragma unroll
    for (int i = 0; i < 4; ++i)
        #pragma unroll
        for (int j = 0; j < 4; ++j) acc[i][j] = (f32x4){0.f, 0.f, 0.f, 0.f};

    LOADX(0); WRITEX(0);
    __syncthreads();

    #pragma unroll 1
    for (int kt = 0; kt < 8; ++kt) {
        const int buf = kt & 1;
        if (kt < 7) LOADX(kt + 1);
        #pragma unroll 1
        for (int s = 0; s < 2; ++s) {
            short8 a[4];
            #pragma unroll
            for (int i = 0; i < 4; ++i)
                a[i] = ldfrag(wp1p, ((wid * 4 + i) * 16 + kt * 2 + s) * 64 + lane);
            __builtin_amdgcn_s_setprio(1);
            #pragma unroll
            for (int j = 0; j < 4; ++j) {
                short8 bb = *(const short8*)(XB + buf * 4864 + (j * 16 + rg) * LDX + (s * 4 + kg) * 8);
                #pragma unroll
                for (int i = 0; i < 4; ++i)
                    acc[i][j] = __builtin_amdgcn_mfma_f32_16x16x32_bf16(a[i], bb, acc[i][j], 0, 0, 0);
            }
            __builtin_amdgcn_s_setprio(0);
        }
        if (kt < 7) WRITEX(buf ^ 1);
        __syncthreads();
    }

    // h1 -> LDS [n][kc] (stride LDH), bias+relu, cvt_pk
    #pragma unroll
    for (int i = 0; i < 4; ++i) {
        const int kc4 = wid * 64 + i * 16 + kg * 4;
        const f32x4 bv = *(const f32x4*)(bp1 + kc4);
        #pragma unroll
        for (int j = 0; j < 4; ++j) {
            const int n = j * 16 + rg;
            uint2 pk;
            pk.x = cvtpk(fmaxf(acc[i][j][0] + bv.x, 0.f), fmaxf(acc[i][j][1] + bv.y, 0.f));
            pk.y = cvtpk(fmaxf(acc[i][j][2] + bv.z, 0.f), fmaxf(acc[i][j][3] + bv.w, 0.f));
            *(uint2*)(sh + n * LDH + kc4) = pk;
        }
    }
    __syncthreads();

    // ------------------------- phase 2: G2 (K=256) -------------------------
    f32x4 acc2[4][4];
    #pragma unroll
    for (int i = 0; i < 4; ++i)
        #pragma unroll
        for (int j = 0; j < 4; ++j) acc2[i][j] = (f32x4){0.f, 0.f, 0.f, 0.f};

    #pragma unroll 1
    for (int S = 0; S < 8; ++S) {
        short8 a[4];
        #pragma unroll
        for (int i = 0; i < 4; ++i)
            a[i] = ldfrag(wp2p, ((wid * 4 + i) * 8 + S) * 64 + lane);
        __builtin_amdgcn_s_setprio(1);
        #pragma unroll
        for (int j = 0; j < 4; ++j) {
            short8 bb = *(const short8*)(sh + (j * 16 + rg) * LDH + S * 32 + kg * 8);
            #pragma unroll
            for (int i = 0; i < 4; ++i)
                acc2[i][j] = __builtin_amdgcn_mfma_f32_16x16x32_bf16(a[i], bb, acc2[i][j], 0, 0, 0);
        }
        __builtin_amdgcn_s_setprio(0);
    }
    __syncthreads();   // all H1 reads done

    // q2 -> same LDS region, bias+relu, cvt_pk
    #pragma unroll
    for (int i = 0; i < 4; ++i) {
        const int kc4 = wid * 64 + i * 16 + kg * 4;
        const f32x4 bv = *(const f32x4*)(bp2 + kc4);
        #pragma unroll
        for (int j = 0; j < 4; ++j) {
            const int n = j * 16 + rg;
            uint2 pk;
            pk.x = cvtpk(fmaxf(acc2[i][j][0] + bv.x, 0.f), fmaxf(acc2[i][j][1] + bv.y, 0.f));
            pk.y = cvtpk(fmaxf(acc2[i][j][2] + bv.z, 0.f), fmaxf(acc2[i][j][3] + bv.w, 0.f));
            *(uint2*)(sh + n * LDH + kc4) = pk;
        }
    }
    __syncthreads();

    // ------------------- phase 3: G3 + in-register softmax ------------------
    f32x4 s1[10];
    #pragma unroll
    for (int i = 0; i < 10; ++i) s1[i] = (f32x4){0.f, 0.f, 0.f, 0.f};
    #pragma unroll 1
    for (int s = 0; s < 8; ++s) {
        short8 bq = *(const short8*)(sh + (wid * 16 + rg) * LDH + s * 32 + kg * 8);
        __builtin_amdgcn_s_setprio(1);
        #pragma unroll
        for (int i = 0; i < 10; ++i) {
            short8 a = ldfrag(kyp, (i * 8 + s) * 64 + lane);
            s1[i] = __builtin_amdgcn_mfma_f32_16x16x32_bf16(a, bq, s1[i], 0, 0, 0);
        }
        __builtin_amdgcn_s_setprio(0);
    }
    float mx = -3.0e38f;
    #pragma unroll
    for (int i = 0; i < 9; ++i)
        #pragma unroll
        for (int r = 0; r < 4; ++r) mx = fmaxf(mx, s1[i][r]);
    #pragma unroll
    for (int r = 0; r < 4; ++r) if (kg * 4 + r < 6) mx = fmaxf(mx, s1[9][r]);
    mx = fmaxf(mx, __shfl_xor(mx, 16));
    mx = fmaxf(mx, __shfl_xor(mx, 32));
    float l = 0.f;
    #pragma unroll
    for (int i = 0; i < 10; ++i)
        #pragma unroll
        for (int r = 0; r < 4; ++r) {
            const bool valid = (i < 9) || (kg * 4 + r < 6);
            float e = valid ? __expf((s1[i][r] - mx) * 0.0625f) : 0.f;
            s1[i][r] = e; l += e;
        }
    l += __shfl_xor(l, 16);
    l += __shfl_xor(l, 32);
    const float inv = 1.f / l;
    __syncthreads();   // all Q reads done

    // P -> LDS [n][kp] (stride LDP), normalized bf16, cvt_pk
    #pragma unroll
    for (int i = 0; i < 10; ++i) {
        uint2 pk;
        pk.x = cvtpk(s1[i][0] * inv, s1[i][1] * inv);
        pk.y = cvtpk(s1[i][2] * inv, s1[i][3] * inv);
        *(uint2*)(sh + (wid * 16 + rg) * LDP + i * 16 + kg * 4) = pk;
    }
    __syncthreads();

    // ------------------------- phase 4: G4 (K=160) -------------------------
    f32x4 acc4[4][4];
    #pragma unroll
    for (int i = 0; i < 4; ++i)
        #pragma unroll
        for (int j = 0; j < 4; ++j) acc4[i][j] = (f32x4){0.f, 0.f, 0.f, 0.f};
    #pragma unroll 1
    for (int s = 0; s < 5; ++s) {
        short8 a[4];
        #pragma unroll
        for (int i = 0; i < 4; ++i)
            a[i] = ldfrag(vbp, ((wid * 4 + i) * 5 + s) * 64 + lane);
        __builtin_amdgcn_s_setprio(1);
        #pragma unroll
        for (int j = 0; j < 4; ++j) {
            short8 bb = *(const short8*)(sh + (j * 16 + rg) * LDP + s * 32 + kg * 8);
            #pragma unroll
            for (int i = 0; i < 4; ++i)
                acc4[i][j] = __builtin_amdgcn_mfma_f32_16x16x32_bf16(a[i], bb, acc4[i][j], 0, 0, 0);
        }
        __builtin_amdgcn_s_setprio(0);
    }
    __syncthreads();   // all P reads done

    // context -> LDS [n][kc] (stride LDH), cvt_pk
    #pragma unroll
    for (int i = 0; i < 4; ++i) {
        const int kc4 = wid * 64 + i * 16 + kg * 4;
        #pragma unroll
        for (int j = 0; j < 4; ++j) {
            const int n = j * 16 + rg;
            uint2 pk;
            pk.x = cvtpk(acc4[i][j][0], acc4[i][j][1]);
            pk.y = cvtpk(acc4[i][j][2], acc4[i][j][3]);
            *(uint2*)(sh + n * LDH + kc4) = pk;
        }
    }
    __syncthreads();

    // ---------------- phase 5: G5 (K=256, M=512, two halves) ----------------
    #pragma unroll 1
    for (int h2 = 0; h2 < 2; ++h2) {
        f32x4 a5[4][4];
        #pragma unroll
        for (int i = 0; i < 4; ++i)
            #pragma unroll
            for (int j = 0; j < 4; ++j) a5[i][j] = (f32x4){0.f, 0.f, 0.f, 0.f};
        #pragma unroll 1
        for (int S = 0; S < 8; ++S) {
            short8 a[4];
            #pragma unroll
            for (int i = 0; i < 4; ++i)
                a[i] = ldfrag(wup, ((h2 * 16 + wid * 4 + i) * 8 + S) * 64 + lane);
            __builtin_amdgcn_s_setprio(1);
            #pragma unroll
            for (int j = 0; j < 4; ++j) {
                short8 bb = *(const short8*)(sh + (j * 16 + rg) * LDH + S * 32 + kg * 8);
                #pragma unroll
                for (int i = 0; i < 4; ++i)
                    a5[i][j] = __builtin_amdgcn_mfma_f32_16x16x32_bf16(a[i], bb, a5[i][j], 0, 0, 0);
            }
            __builtin_amdgcn_s_setprio(0);
        }
        #pragma unroll
        for (int i = 0; i < 4; ++i) {
            const int c4 = h2 * 256 + wid * 64 + i * 16 + kg * 4;
            const f32x4 bv = *(const f32x4*)(bu + c4);
            #pragma unroll
            for (int j = 0; j < 4; ++j) {
                const int n = n0 + j * 16 + rg;
                ob[(long)(c4 + 0) * NPX + n] = fmaxf(a5[i][j][0] + bv.x, 0.f);
                ob[(long)(c4 + 1) * NPX + n] = fmaxf(a5[i][j][1] + bv.y, 0.f);
                ob[(long)(c4 + 2) * NPX + n] = fmaxf(a5[i][j][2] + bv.z, 0.f);
                ob[(long)(c4 + 3) * NPX + n] = fmaxf(a5[i][j][3] + bv.w, 0.f);
            }
        }
    }
}

// ===========================================================================
// prep: blocks 0..511 pack wp1/wp2/wu into MFMA A-frag bf16 order; blocks
// 512..591: LDS-tiled 64x64 transposes of w_o1/w_d/w_o2 to [c][kc] fp32.
// ===========================================================================
__global__ __launch_bounds__(256)
void prep_kernel(const float* __restrict__ w_p1, const float* __restrict__ w_p2,
                 const float* __restrict__ w_u,  const float* __restrict__ w_o1,
                 const float* __restrict__ w_o2, const float* __restrict__ w_d,
                 u16* __restrict__ wp1p, u16* __restrict__ wp2p,
                 u16* __restrict__ wup, float* __restrict__ wo1T,
                 float* __restrict__ wdT, float* __restrict__ wo2T)
{
    const int bx = blockIdx.x;
    const int tid = threadIdx.x;
    if (bx < 512) {
        const int i = bx * 256 + tid;   // < 131072
        const int j = i & 7, l = (i >> 3) & 63;
        {   // wp1: M=256, K=512, NS=16
            const int S = (i >> 9) & 15, R = i >> 13;
            wp1p[i] = f2bf(w_p1[(long)(R * 16 + (l & 15)) * CIN + S * 32 + ((l >> 4) << 3) + j]);
        }
        {   // wu: M=512, K=256, NS=8
            const int S = (i >> 9) & 7, R = i >> 12;
            wup[i] = f2bf(w_u[(long)(R * 16 + (l & 15)) * KC + S * 32 + ((l >> 4) << 3) + j]);
        }
        if (i < 65536) {
            // wp2: M=256, K=256, NS=8
            const int S = (i >> 9) & 7, R = i >> 12;
            wp2p[i] = f2bf(w_p2[(long)(R * 16 + (l & 15)) * KC + S * 32 + ((l >> 4) << 3) + j]);
        }
        return;
    }
    // ---- transpose tiles: src [256][C] -> dst [C][256] ----
    __shared__ float T[64][65];
    int tb = bx - 512;
    const float* src; float* dst; int srcC;
    if (tb < 32)      { src = w_o1; dst = wo1T; srcC = CIN; }
    else if (tb < 64) { tb -= 32; src = w_d; dst = wdT; srcC = CIN; }
    else              { tb -= 64; src = w_o2; dst = wo2T; srcC = KC; }
    const int r0 = (tb & 3) * 64, c0 = (tb >> 2) * 64;
    const int lr = tid >> 6, lc = tid & 63;
    #pragma unroll
    for (int p = 0; p < 16; ++p)
        T[p * 4 + lr][lc] = src[(long)(r0 + p * 4 + lr) * srcC + c0 + lc];
    __syncthreads();
    #pragma unroll
    for (int p = 0; p < 16; ++p)
        dst[(long)(c0 + p * 4 + lr) * KC + r0 + lc] = T[lc][p * 4 + lr];
}

// ===========================================================================
// kv: merged kv1+kv2 — block = 2 kp rows x 256 kc threads, grid (80, NB).
// ===========================================================================
__global__ __launch_bounds__(256)
void kv_kernel(const float* __restrict__ proxy,
               const float* __restrict__ wo1T, const float* __restrict__ b_o1,
               const float* __restrict__ wdT,  const float* __restrict__ b_d,
               const float* __restrict__ wo2T, const float* __restrict__ b_o2,
               u16* __restrict__ keyp, u16* __restrict__ vp)
{
    __shared__ float PX[CIN * 2];   // proxy [c][q]  4 KB
    __shared__ float HL[2][KC];     // hidden[q][kc] 2 KB
    const int kp0 = blockIdx.x * 2;
    const int b   = blockIdx.y;
    const int kc  = threadIdx.x;    // 0..255

    #pragma unroll
    for (int it = 0; it < 4; ++it) {
        const int idx = it * 256 + kc;
        const int q = idx & 1, c = idx >> 1;
        const int kp = kp0 + q;
        PX[c * 2 + q] = (kp < KP) ? proxy[(long)b * CIN * KP + (long)c * KP + kp] : 0.f;
    }
    __syncthreads();

    float ah[2] = {0.f, 0.f}, av[2] = {0.f, 0.f};
    #pragma unroll 1
    for (int c0 = 0; c0 < CIN; c0 += 8) {
        float w1[8], wd[8];
        #pragma unroll
        for (int e = 0; e < 8; ++e) {
            w1[e] = wo1T[(long)(c0 + e) * KC + kc];
            wd[e] = wdT [(long)(c0 + e) * KC + kc];
        }
        #pragma unroll
        for (int e = 0; e < 8; ++e)
            #pragma unroll
            for (int q = 0; q < 2; ++q) {
                const float p = PX[(c0 + e) * 2 + q];
                ah[q] += w1[e] * p;
                av[q] += wd[e] * p;
            }
    }
    const float bo1 = b_o1[kc], bd = b_d[kc];
    #pragma unroll
    for (int q = 0; q < 2; ++q) {
        const int kp = kp0 + q;
        HL[q][kc] = fmaxf(ah[q] + bo1, 0.f);
        const float vv = (kp < KP) ? fmaxf(av[q] + bd, 0.f) : 0.f;
        const int idx2 = (((kc >> 4) * 5 + (kp >> 5)) * 64 +
                          ((kp >> 3) & 3) * 16 + (kc & 15)) * 8 + (kp & 7);
        vp[(long)b * 40960 + idx2] = f2bf(vv);
    }
    __syncthreads();

    float ak[2] = {0.f, 0.f};
    #pragma unroll 1
    for (int c0 = 0; c0 < KC; c0 += 8) {
        float w2[8];
        #pragma unroll
        for (int e = 0; e < 8; ++e)
            w2[e] = wo2T[(long)(c0 + e) * KC + kc];
        #pragma unroll
        for (int e = 0; e < 8; ++e)
            #pragma unroll
            for (int q = 0; q < 2; ++q)
                ak[q] += w2[e] * HL[q][c0 + e];
    }
    const float bo2 = b_o2[kc];
    #pragma unroll
    for (int q = 0; q < 2; ++q) {
        const int kp = kp0 + q;
        const float v = (kp < KP) ? fmaxf(ak[q] + bo2, 0.f) : 0.f;
        const int idx = (((kp >> 4) * 8 + (kc >> 5)) * 64 +
                         ((kc >> 3) & 3) * 16 + (kp & 15)) * 8 + (kc & 7);
        keyp[(long)b * 40960 + idx] = f2bf(v);
    }
}

extern "C" void kernel_launch(void* const* d_in, const int* in_sizes, int n_in,
                              void* d_out, int out_size, void* d_ws, size_t ws_size,
                              hipStream_t stream)
{
    const float* x     = (const float*)d_in[0];
    const float* proxy = (const float*)d_in[1];
    const float* w_p1  = (const float*)d_in[2];
    const float* b_p1  = (const float*)d_in[3];
    const float* w_p2  = (const float*)d_in[4];
    const float* b_p2  = (const float*)d_in[5];
    const float* w_o1  = (const float*)d_in[6];
    const float* b_o1  = (const float*)d_in[7];
    const float* w_o2  = (const float*)d_in[8];
    const float* b_o2  = (const float*)d_in[9];
    const float* w_d   = (const float*)d_in[10];
    const float* b_d   = (const float*)d_in[11];
    const float* w_u   = (const float*)d_in[12];
    const float* b_u   = (const float*)d_in[13];
    float* out = (float*)d_out;
    (void)in_sizes; (void)n_in; (void)out_size; (void)ws_size;

    char* ws = (char*)d_ws;
    size_t off = 0;
    auto alloc = [&](size_t bytes) { size_t o = off; off += (bytes + 255) & ~(size_t)255; return o; };

    u16*   wp1p = (u16*)  (ws + alloc((size_t)131072 * 2));
    u16*   wp2p = (u16*)  (ws + alloc((size_t)65536 * 2));
    u16*   wup  = (u16*)  (ws + alloc((size_t)131072 * 2));
    float* wo1T = (float*)(ws + alloc((size_t)131072 * 4));
    float* wdT  = (float*)(ws + alloc((size_t)131072 * 4));
    float* wo2T = (float*)(ws + alloc((size_t)65536 * 4));
    u16*   keyp = (u16*)  (ws + alloc((size_t)NB * 40960 * 2));
    u16*   vp   = (u16*)  (ws + alloc((size_t)NB * 40960 * 2));

    prep_kernel<<<592, 256, 0, stream>>>(
        w_p1, w_p2, w_u, w_o1, w_o2, w_d, wp1p, wp2p, wup, wo1T, wdT, wo2T);
    kv_kernel<<<dim3(80, NB), 256, 0, stream>>>(
        proxy, wo1T, b_o1, wdT, b_d, wo2T, b_o2, keyp, vp);
    fused_kernel<<<dim3(NPX / 64, 1, NB), 256, 0, stream>>>(
        wp1p, x, wp2p, b_p1, b_p2, keyp, vp, wup, b_u, out);
}